// Round 8
// baseline (330.652 us; speedup 1.0000x reference)
//
#include <hip/hip_runtime.h>
#include <hip/hip_bf16.h>
#include <cstdint>

typedef __bf16 bf16x4 __attribute__((ext_vector_type(4)));
typedef float  f32x4  __attribute__((ext_vector_type(4)));
typedef int    i32x4  __attribute__((ext_vector_type(4)));
typedef int    i32x8  __attribute__((ext_vector_type(8)));

#define B_ROWS 4096
#define IN_DIM 1024
#define HIDDEN 8192
#define KEEP   256

using gptr_t = const __attribute__((address_space(1))) void*;
using lptr_t = __attribute__((address_space(3))) void*;

__device__ __forceinline__ void async_load16(const void* g, void* l) {
    gptr_t gp = reinterpret_cast<gptr_t>(reinterpret_cast<uintptr_t>(g));
    lptr_t lp = reinterpret_cast<lptr_t>(reinterpret_cast<uintptr_t>(l));
    __builtin_amdgcn_global_load_lds(gp, lp, 16, 0, 0);
}

__device__ __forceinline__ unsigned char f32_to_fp8(float v) {
    return (unsigned char)(__builtin_amdgcn_cvt_pk_fp8_f32(v, v, 0, false) & 0xFF);
}

// ---------------------------------------------------------------------------
// ENCODE GEMM — r6 config, VERBATIM BODY. C[M,N] = A[M,K] @ B[N,K]^T, fp8
// e4m3, MX MFMA (unit scales), fp32 accum, fp8 C out.
// HISTORY (measured): r6 = best ~48-49us, MfmaUtil 26%, Occ 33%. All
// restructures lost: r9 ring 54.5 / r10 4-phase 60.0 / r11 split-bar 59.5
// (1-blk/CU kills TLP overlap, m114); r8 BKB=256 59; r5 atomic splitK 81.
// R6: XCD-chunked remap (SWZ) -> FETCH unchanged 136MB, dur unchanged =>
// over-fetch is NOT cross-XCD B-reuse (or lin&7!=XCD); encode is at its
// additive LDS+MFMA structural ceiling, NOT fetch-BW-bound (136MB@L3-speed
// = 25us < 49us). SWZ kept (neutral). DO NOT RESTRUCTURE.
// ---------------------------------------------------------------------------
template<int BM, int BN, int WROWS, int WCOLS, int SWZ>
__global__ __launch_bounds__(256, 3)
void gemm_nt_fp8(const unsigned char* __restrict__ A, int lda,
                 const unsigned char* __restrict__ Bm, int ldb,
                 void* __restrict__ Cout, int M, int N, int Kloop)
{
    constexpr int BKB = 128;
    constexpr int WTM = BM / WROWS / 16;
    constexpr int WTN = BN / WCOLS / 16;

    __shared__ __align__(16) unsigned char As[BM * BKB];
    __shared__ __align__(16) unsigned char Bs[BN * BKB];

    const int tid  = threadIdx.x;
    const int wave = tid >> 6;
    const int lane = tid & 63;

    long long block_m, block_n;
    if constexpr (SWZ == 1) {
        const int lin = blockIdx.y * gridDim.x + blockIdx.x;
        const int x   = lin & 7;
        const int j   = lin >> 3;
        const int jj  = j & 31;
        const int c   = j >> 5;
        const int nb  = x * 8 + (jj & 7);
        const int mb  = c * 4 + (jj >> 3);
        block_m = (long long)mb * BM;
        block_n = (long long)nb * BN;
    } else {
        block_m = (long long)blockIdx.y * BM;
        block_n = (long long)blockIdx.x * BN;
    }

    const int wm = (wave / WCOLS) * (WTM * 16);
    const int wn = (wave % WCOLS) * (WTN * 16);

    f32x4 acc[WTM][WTN] = {};

    constexpr int A_CALLS = BM / 32;
    constexpr int B_CALLS = BN / 32;
    const int sub_row = lane >> 3;
    const int slot    = lane & 7;
    const int kg_sw   = (slot ^ sub_row) * 16;
    const int koff_n  = slot * 16;

    const int lm = lane & 15;
    const int lq = lane >> 4;

    for (int kt = 0; kt < Kloop; kt += BKB) {
        #pragma unroll
        for (int c = 0; c < A_CALLS; ++c) {
            const int row = (wave * A_CALLS + c) * 8 + sub_row;
            async_load16(A + (block_m + row) * (long long)lda + kt + kg_sw,
                         &As[row * BKB + koff_n]);
        }
        #pragma unroll
        for (int c = 0; c < B_CALLS; ++c) {
            const int row = (wave * B_CALLS + c) * 8 + sub_row;
            async_load16(Bm + (block_n + row) * (long long)ldb + kt + kg_sw,
                         &Bs[row * BKB + koff_n]);
        }
        __syncthreads();

        i32x8 af[WTM], bfq[WTN];
        #pragma unroll
        for (int i = 0; i < WTM; ++i) {
            const int r = wm + i * 16 + lm;
            const i32x4 lo = *(const i32x4*)&As[r * BKB + (((2 * lq) ^ (r & 7)) * 16)];
            const i32x4 hi = *(const i32x4*)&As[r * BKB + (((2 * lq + 1) ^ (r & 7)) * 16)];
            af[i] = i32x8{lo.x, lo.y, lo.z, lo.w, hi.x, hi.y, hi.z, hi.w};
        }
        #pragma unroll
        for (int j = 0; j < WTN; ++j) {
            const int r = wn + j * 16 + lm;
            const i32x4 lo = *(const i32x4*)&Bs[r * BKB + (((2 * lq) ^ (r & 7)) * 16)];
            const i32x4 hi = *(const i32x4*)&Bs[r * BKB + (((2 * lq + 1) ^ (r & 7)) * 16)];
            bfq[j] = i32x8{lo.x, lo.y, lo.z, lo.w, hi.x, hi.y, hi.z, hi.w};
        }
        #pragma unroll
        for (int i = 0; i < WTM; ++i)
            #pragma unroll
            for (int j = 0; j < WTN; ++j)
                acc[i][j] = __builtin_amdgcn_mfma_scale_f32_16x16x128_f8f6f4(
                    af[i], bfq[j], acc[i][j],
                    0, 0, 0, 0x7F7F7F7F, 0, 0x7F7F7F7F);
        __syncthreads();
    }

    // D[m][n]: n = lane&15, m = 4*(lane>>4)+r
    const int rbase = lq * 4;
    unsigned char* Hh = (unsigned char*)Cout;
    #pragma unroll
    for (int i = 0; i < WTM; ++i)
        #pragma unroll
        for (int j = 0; j < WTN; ++j)
            #pragma unroll
            for (int r = 0; r < 4; ++r) {
                const long long m = block_m + wm + i * 16 + rbase + r;
                const long long n = block_n + wn + j * 16 + lm;
                Hh[m * N + n] = f32_to_fp8(acc[i][j][r]);
            }
}

// ---------------------------------------------------------------------------
// prep: one dispatch, three ranges.
//  blocks [0, 8192):        Wenc fp32 -> fp8 linear cast
//  blocks [8192, 10240):    Wdec fp32 [1024][8192] -> fp8 TRANSPOSED
//                           WdecT [8192][1024] via 64x64 LDS tile
//                           (sparse decode gathers columns as rows)
//  blocks [10240, 14336):   x row-normalize -> fp8
// ---------------------------------------------------------------------------
__global__ __launch_bounds__(256)
void prep(const float* __restrict__ Wenc, const float* __restrict__ Wdec,
          const float* __restrict__ x,
          unsigned char* __restrict__ WencB, unsigned char* __restrict__ WdecT,
          unsigned char* __restrict__ xn)
{
    constexpr int EBLK = HIDDEN * IN_DIM / 4 / 256;   // 8192
    constexpr int TBLK = (HIDDEN / 64) * (IN_DIM / 64); // 2048
    const int t = threadIdx.x;

    if (blockIdx.x < EBLK) {
        const int i = blockIdx.x * 256 + t;
        const float4 v = ((const float4*)Wenc)[i];
        int p = __builtin_amdgcn_cvt_pk_fp8_f32(v.x, v.y, 0, false);
        p     = __builtin_amdgcn_cvt_pk_fp8_f32(v.z, v.w, p, true);
        ((int*)WencB)[i] = p;
    } else if (blockIdx.x < EBLK + TBLK) {
        // transpose-cast one 64(h) x 64(i) tile
        __shared__ unsigned int Ld[64][17];
        const int tb = blockIdx.x - EBLK;
        const int h0 = (tb & 127) * 64;          // HIDDEN/64 = 128
        const int i0 = (tb >> 7) * 64;
        const int il = t >> 2;                   // 0..63 input row (i)
        const int q4 = (t & 3) * 4;              // word offset in tile row
        #pragma unroll
        for (int k = 0; k < 4; ++k) {
            const float4 v = *(const float4*)&Wdec[(size_t)(i0 + il) * HIDDEN + h0 + (q4 + k) * 4];
            int p = __builtin_amdgcn_cvt_pk_fp8_f32(v.x, v.y, 0, false);
            p     = __builtin_amdgcn_cvt_pk_fp8_f32(v.z, v.w, p, true);
            Ld[il][q4 + k] = (unsigned int)p;
        }
        __syncthreads();
        const int hl = t >> 2;                   // 0..63 output row (h)
        const int ws = (t & 3) * 4;              // output word group
        const int bsh = 8 * (hl & 3);
        const int wid = hl >> 2;
        uint4 ov;
        unsigned int* op = (unsigned int*)&ov;
        #pragma unroll
        for (int k = 0; k < 4; ++k) {
            unsigned int ow = 0;
            #pragma unroll
            for (int b = 0; b < 4; ++b)
                ow |= ((Ld[4 * (ws + k) + b][wid] >> bsh) & 0xFFu) << (8 * b);
            op[k] = ow;
        }
        *(uint4*)&WdecT[(size_t)(h0 + hl) * IN_DIM + i0 + ws * 4] = ov;
    } else {
        const int row = blockIdx.x - (EBLK + TBLK);
        const float4 v = ((const float4*)(x + (long long)row * IN_DIM))[t];
        float ss = v.x * v.x + v.y * v.y + v.z * v.z + v.w * v.w;
        #pragma unroll
        for (int off = 32; off > 0; off >>= 1) ss += __shfl_down(ss, off);
        __shared__ float part[4];
        if ((t & 63) == 0) part[t >> 6] = ss;
        __syncthreads();
        const float tot = part[0] + part[1] + part[2] + part[3];
        const float inv = 1.0f / fmaxf(sqrtf(tot), 1e-12f);
        int p = __builtin_amdgcn_cvt_pk_fp8_f32(v.x * inv, v.y * inv, 0, false);
        p     = __builtin_amdgcn_cvt_pk_fp8_f32(v.z * inv, v.w * inv, p, true);
        ((int*)(xn + (long long)row * IN_DIM))[t] = p;
    }
}

// ---------------------------------------------------------------------------
// topk_decode — R15 fusion of {topk + decode-GEMM + reduce_out}.
// One block per row. Phase 1: hist8 LDS histogram -> threshold T (VERBATIM
// proven mask8 logic; register replacements r12/r14 both measured slower —
// keep the atomics). Phase 2: build kept (idx,val) list in LDS (cap 2048;
// ties-safe: threshold tie class ~O(100) for clustered fp8 values).
// Phase 3: sparse accumulate out[col] = x + gate * sum_j val_j*WdecT[j][col]
// — only ~300 of 8192 columns survive (97% of the old dense 68.7GF decode
// was multiplying zeros). W-gather is a coalesced 1KB row read per entry
// (WdecT transposed in prep); ~1.26GB L2-resident traffic ~ 36us bound.
// Replaces: topk 32MB H-rewrite + dense decode 48.5us + reduce 8.3us +
// Part buffer + 2 launches.
// ---------------------------------------------------------------------------
__global__ __launch_bounds__(256)
void topk_decode(const unsigned int* __restrict__ H,
                 const unsigned char* __restrict__ Wt,   // [HIDDEN][IN_DIM] fp8
                 const float* __restrict__ x,
                 const float* __restrict__ gate,
                 float* __restrict__ out)
{
    __shared__ unsigned int hist8[256 * 8];
    __shared__ unsigned int sT;
    __shared__ unsigned int sCnt;
    __shared__ unsigned int list[2048];
    const int t = threadIdx.x;
    const unsigned int* row = H + (size_t)blockIdx.x * (HIDDEN / 4);

    #pragma unroll
    for (int i = 0; i < 8; ++i) hist8[i * 256 + t] = 0;
    if (t == 0) sCnt = 0;
    __syncthreads();

    unsigned int rw[8];
    const int cp = t & 7;
    #pragma unroll
    for (int i = 0; i < 8; ++i) {
        rw[i] = row[i * 256 + t];
        #pragma unroll
        for (int e = 0; e < 4; ++e) {
            const unsigned int b = (rw[i] >> (8 * e)) & 0xFFu;
            const unsigned int k = b ^ ((b & 0x80u) ? 0xFFu : 0x80u);
            atomicAdd(&hist8[k * 8 + cp], 1u);
        }
    }
    __syncthreads();

    unsigned int cnt0 = 0;
    #pragma unroll
    for (int c = 0; c < 8; ++c) cnt0 += hist8[t * 8 + c];
    __syncthreads();
    hist8[t] = cnt0;
    __syncthreads();

    if (t < 64) {
        const uint4 c4 = *(const uint4*)&hist8[4 * t];
        const unsigned s3 = c4.w;
        const unsigned s2 = c4.z + s3;
        const unsigned s1 = c4.y + s2;
        const unsigned s0 = c4.x + s1;
        unsigned inc = s0;
        #pragma unroll
        for (int off = 1; off < 64; off <<= 1) {
            unsigned o = __shfl_down(inc, off);
            if (t + off >= 64) o = 0;
            inc += o;
        }
        const unsigned carry = inc - s0;
        const unsigned a0 = s0 + carry, a1 = s1 + carry;
        const unsigned a2 = s2 + carry, a3 = s3 + carry;
        if (a0 >= KEEP && a1 < KEEP)    sT = 4u * t + 0u;
        if (a1 >= KEEP && a2 < KEEP)    sT = 4u * t + 1u;
        if (a2 >= KEEP && a3 < KEEP)    sT = 4u * t + 2u;
        if (a3 >= KEEP && carry < KEEP) sT = 4u * t + 3u;
    }
    __syncthreads();
    const unsigned int T = sT;

    // Phase 2: kept list (idx<<8 | fp8 byte)
    #pragma unroll
    for (int i = 0; i < 8; ++i) {
        #pragma unroll
        for (int e = 0; e < 4; ++e) {
            const unsigned int b = (rw[i] >> (8 * e)) & 0xFFu;
            const unsigned int k = b ^ ((b & 0x80u) ? 0xFFu : 0x80u);
            if (k >= T) {
                const unsigned int slot = atomicAdd(&sCnt, 1u);
                if (slot < 2048u)
                    list[slot] = ((unsigned int)(4 * (i * 256 + t) + e) << 8) | b;
            }
        }
    }
    __syncthreads();
    const int cnt = (int)min(sCnt, 2048u);

    // Phase 3: sparse accumulate, 2-wide MLP.
    float a0 = 0.f, a1 = 0.f, a2 = 0.f, a3 = 0.f;
    int s = 0;
    for (; s + 1 < cnt; s += 2) {
        const unsigned int e0 = list[s], e1 = list[s + 1];
        const unsigned int w0 = *(const unsigned int*)&Wt[(size_t)(e0 >> 8) * IN_DIM + 4 * t];
        const unsigned int w1 = *(const unsigned int*)&Wt[(size_t)(e1 >> 8) * IN_DIM + 4 * t];
        const float v0 = __builtin_amdgcn_cvt_f32_fp8((int)(e0 & 0xFFu), 0);
        const float v1 = __builtin_amdgcn_cvt_f32_fp8((int)(e1 & 0xFFu), 0);
        a0 += v0 * __builtin_amdgcn_cvt_f32_fp8((int)w0, 0);
        a1 += v0 * __builtin_amdgcn_cvt_f32_fp8((int)w0, 1);
        a2 += v0 * __builtin_amdgcn_cvt_f32_fp8((int)w0, 2);
        a3 += v0 * __builtin_amdgcn_cvt_f32_fp8((int)w0, 3);
        a0 += v1 * __builtin_amdgcn_cvt_f32_fp8((int)w1, 0);
        a1 += v1 * __builtin_amdgcn_cvt_f32_fp8((int)w1, 1);
        a2 += v1 * __builtin_amdgcn_cvt_f32_fp8((int)w1, 2);
        a3 += v1 * __builtin_amdgcn_cvt_f32_fp8((int)w1, 3);
    }
    if (s < cnt) {
        const unsigned int e0 = list[s];
        const unsigned int w0 = *(const unsigned int*)&Wt[(size_t)(e0 >> 8) * IN_DIM + 4 * t];
        const float v0 = __builtin_amdgcn_cvt_f32_fp8((int)(e0 & 0xFFu), 0);
        a0 += v0 * __builtin_amdgcn_cvt_f32_fp8((int)w0, 0);
        a1 += v0 * __builtin_amdgcn_cvt_f32_fp8((int)w0, 1);
        a2 += v0 * __builtin_amdgcn_cvt_f32_fp8((int)w0, 2);
        a3 += v0 * __builtin_amdgcn_cvt_f32_fp8((int)w0, 3);
    }

    const float4 xv = ((const float4*)x)[blockIdx.x * (IN_DIM / 4) + t];
    const float4 g  = ((const float4*)gate)[t];
    float4 o;
    o.x = xv.x + g.x * a0;
    o.y = xv.y + g.y * a1;
    o.z = xv.z + g.z * a2;
    o.w = xv.w + g.w * a3;
    ((float4*)out)[blockIdx.x * (IN_DIM / 4) + t] = o;
}

// ---------------------------------------------------------------------------
extern "C" void kernel_launch(void* const* d_in, const int* in_sizes, int n_in,
                              void* d_out, int out_size, void* d_ws, size_t ws_size,
                              hipStream_t stream)
{
    const float* x    = (const float*)d_in[0];   // [4096,1024]
    const float* Wenc = (const float*)d_in[1];   // [8192,1024]
    const float* Wdec = (const float*)d_in[2];   // [1024,8192]
    const float* gate = (const float*)d_in[3];   // [1024]
    float* out = (float*)d_out;

    char* ws = (char*)d_ws;
    unsigned char* xn    = (unsigned char*)(ws);                        //  4 MB
    unsigned char* WencB = (unsigned char*)(ws + (size_t)( 4 << 20));   //  8 MB
    unsigned char* WdecT = (unsigned char*)(ws + (size_t)(12 << 20));   //  8 MB
    unsigned char* Hbuf  = (unsigned char*)(ws + (size_t)(20 << 20));   // 32 MB

    constexpr int EBLK = HIDDEN * IN_DIM / 4 / 256;      // 8192
    constexpr int TBLK = (HIDDEN / 64) * (IN_DIM / 64);  // 2048
    prep<<<EBLK + TBLK + B_ROWS, 256, 0, stream>>>(Wenc, Wdec, x, WencB, WdecT, xn);

    // hidden[4096,8192] = xn @ Wenc^T  (fp8 out)
    gemm_nt_fp8<128, 128, 2, 2, 1><<<dim3(HIDDEN / 128, B_ROWS / 128, 1), 256, 0, stream>>>(
        xn, IN_DIM, WencB, IN_DIM, (void*)Hbuf, B_ROWS, HIDDEN, IN_DIM);

    // fused: per-row topk threshold + sparse decode + gate/residual
    topk_decode<<<B_ROWS, 256, 0, stream>>>((const unsigned int*)Hbuf, WdecT,
                                            x, gate, out);
}